// Round 6
// baseline (609.440 us; speedup 1.0000x reference)
//
#include <hip/hip_runtime.h>
#include <hip/hip_bf16.h>
#include <stdint.h>

// R6 = MEASUREMENT ROUND: R2 source verbatim + 2 duplicate gemm1 dispatches.
// t_gemm + launch_gap = (dur_R6 - 489) / 2.  Deliberately slower; buys
// per-kernel attribution the top-5 profile (all >163us harness fills) hides.

typedef _Float16 f16;
typedef _Float16 f16x8 __attribute__((ext_vector_type(8)));
typedef float f32x4 __attribute__((ext_vector_type(4)));

#define B_    32
#define T_    1024
#define TP_   1026
#define C_    512
#define LMAX_ 4096
#define KDIM  1536

// workspace byte offsets (all 256-aligned)
#define XPAD_OFF   0u
#define H1PAD_OFF  33619968u     // 32*1026*512*2
#define W1T_OFF    67239936u
#define W2T_OFF    68812800u
#define YWS_OFF    70385664u
#define TOT_OFF    137494528u
#define IDX_OFF    137495040u

#define AS1C(p) ((const __attribute__((address_space(1))) void*)(p))
#define AS3(p)  ((__attribute__((address_space(3))) void*)(p))

// ---------------------------------------------------------------------------
// prep: xpad = fp16(batch) with zero guard rows at t=-1 and t=T; also zero
// h1pad guard rows (ws is re-poisoned before every launch).
__global__ __launch_bounds__(256) void prep_pad(const float* __restrict__ batch,
                                                f16* __restrict__ xpad,
                                                f16* __restrict__ h1pad) {
    int row = blockIdx.x * 4 + (threadIdx.x >> 6);   // 0 .. B_*TP_-1
    int lane = threadIdx.x & 63;
    int b = row / TP_, tt = row % TP_;
    size_t dsto = (size_t)row * C_ + lane * 8;
    if (tt == 0 || tt == TP_ - 1) {
        f16x8 z = {};
        *(f16x8*)(xpad + dsto) = z;
        *(f16x8*)(h1pad + dsto) = z;
    } else {
        const float* src = batch + ((size_t)(b * T_ + tt - 1)) * C_ + lane * 8;
        float4 v0 = ((const float4*)src)[0];
        float4 v1 = ((const float4*)src)[1];
        f16x8 h;
        h[0] = (f16)v0.x; h[1] = (f16)v0.y; h[2] = (f16)v0.z; h[3] = (f16)v0.w;
        h[4] = (f16)v1.x; h[5] = (f16)v1.y; h[6] = (f16)v1.z; h[7] = (f16)v1.w;
        *(f16x8*)(xpad + dsto) = h;
    }
}

// ---------------------------------------------------------------------------
// prep weights: wt[o][tap*512+i] = w[o][i][tap], fp16.  w is [512][512][3].
__global__ __launch_bounds__(256) void prep_w(const float* __restrict__ w1,
                                              const float* __restrict__ w2,
                                              f16* __restrict__ w1t,
                                              f16* __restrict__ w2t) {
    int o = blockIdx.x;
    const float* w = blockIdx.y ? w2 : w1;
    f16* wt = blockIdx.y ? w2t : w1t;
    for (int j = threadIdx.x; j < KDIM; j += 256) {
        int tap = j >> 9, i = j & 511;
        wt[(size_t)o * KDIM + j] = (f16)w[(size_t)o * KDIM + i * 3 + tap];
    }
}

// ---------------------------------------------------------------------------
// per-batch duration scan + direct inverse-map scatter (searchsorted inverse).
__global__ __launch_bounds__(1024) void scan_kernel(const int* __restrict__ dur,
                                                    const int* __restrict__ tlen,
                                                    int* __restrict__ idxarr,
                                                    int* __restrict__ total,
                                                    float* __restrict__ mel_out) {
    int b = blockIdx.x, t = threadIdx.x;
    __shared__ int sd[1024];
    __shared__ int sv[1024];
    int L = tlen[b];
    int valid = (t < L) ? 1 : 0;
    int d = valid ? dur[b * T_ + t] : 0;
    sd[t] = d; sv[t] = valid;
    __syncthreads();
    for (int off = 1; off < 1024; off <<= 1) {
        int x = 0, y = 0;
        if (t >= off) { x = sd[t - off]; y = sv[t - off]; }
        __syncthreads();
        sd[t] += x; sv[t] += y;
        __syncthreads();
    }
    int totd = sd[1023];
    int cur  = (totd == 0) ? sv[t] : sd[t];
    int prev = (t == 0) ? 0 : ((totd == 0) ? sv[t - 1] : sd[t - 1]);
    for (int f = prev; f < cur; f++) idxarr[b * LMAX_ + f] = t;
    if (t == 1023) {
        int tt = (totd == 0) ? sv[1023] : totd;
        total[b] = tt;
        mel_out[b] = (float)tt;
    }
}

// ---------------------------------------------------------------------------
// implicit-GEMM conv block (R2 structure, best measured): Y = relu(A@Bw^T+b).
// Staging via global_load_lds width=16 into unpadded 128x64 LDS tiles with
// XOR granule swizzle: LDS[r][s] holds global granule s^(r&7).
__global__ __launch_bounds__(256, 2) void gemm_convln(const f16* __restrict__ A,
                                                      const f16* __restrict__ Bw,
                                                      const float* __restrict__ bias,
                                                      float* __restrict__ Y) {
    __shared__ f16 As[128 * 64];
    __shared__ f16 Bs[128 * 64];
    const int tid = threadIdx.x;
    const int lane = tid & 63;
    const int wid = tid >> 6;
    const int m0 = blockIdx.x * 128;
    const int n0 = blockIdx.y * 128;
    const int arow0 = (m0 >> 10) * TP_ + (m0 & 1023);
    const int wm = (wid & 1) * 64;
    const int wn = (wid >> 1) * 64;

    f32x4 acc[4][4];
#pragma unroll
    for (int i = 0; i < 4; i++)
#pragma unroll
        for (int j = 0; j < 4; j++) acc[i][j] = (f32x4){0.f, 0.f, 0.f, 0.f};

    const int srow = lane >> 3;                    // 0..7
    const int gmem = (lane & 7) ^ srow;            // swizzled source granule
    const f16* aBase = A + (size_t)(arow0 + wid * 8 + srow * 0) * C_;  // see below
    // NOTE: keep exact R2 addressing:
    const f16* aB = A + (size_t)(arow0 + wid * 8 + srow) * C_ + gmem * 8;
    const f16* bB = Bw + (size_t)(n0 + wid * 8 + srow) * KDIM + gmem * 8;
    (void)aBase;

    for (int kk = 0; kk < KDIM; kk += 64) {
        __syncthreads();
#pragma unroll
        for (int i = 0; i < 4; i++) {
            __builtin_amdgcn_global_load_lds(AS1C(aB + (size_t)(i * 32) * C_ + kk),
                                             AS3(&As[(wid * 8 + i * 32) * 64]), 16, 0, 0);
            __builtin_amdgcn_global_load_lds(AS1C(bB + (size_t)(i * 32) * KDIM + kk),
                                             AS3(&Bs[(wid * 8 + i * 32) * 64]), 16, 0, 0);
        }
        __syncthreads();   // drains vmcnt -> LDS tiles complete
#pragma unroll
        for (int ks = 0; ks < 2; ks++) {
            const int slot = ((ks << 2) + (lane >> 4)) ^ (lane & 7);
            f16x8 af[4], bf[4];
#pragma unroll
            for (int mi = 0; mi < 4; mi++)
                af[mi] = *(const f16x8*)&As[(wm + mi * 16 + (lane & 15)) * 64 + slot * 8];
#pragma unroll
            for (int ni = 0; ni < 4; ni++)
                bf[ni] = *(const f16x8*)&Bs[(wn + ni * 16 + (lane & 15)) * 64 + slot * 8];
#pragma unroll
            for (int mi = 0; mi < 4; mi++)
#pragma unroll
                for (int ni = 0; ni < 4; ni++)
                    acc[mi][ni] = __builtin_amdgcn_mfma_f32_16x16x32_f16(
                        af[mi], bf[ni], acc[mi][ni], 0, 0, 0);
        }
    }

    const int col = lane & 15;
    const int row4 = (lane >> 4) * 4;
#pragma unroll
    for (int ni = 0; ni < 4; ni++) {
        int n = n0 + wn + ni * 16 + col;
        float bn = bias[n];
#pragma unroll
        for (int mi = 0; mi < 4; mi++) {
#pragma unroll
            for (int r = 0; r < 4; r++) {
                int m = m0 + wm + mi * 16 + row4 + r;
                float v = acc[mi][ni][r] + bn;
                Y[(size_t)m * C_ + n] = v > 0.f ? v : 0.f;
            }
        }
    }
}

// ---------------------------------------------------------------------------
// LayerNorm over C=512, wave per row, write fp16 into padded h1 buffer.
__global__ __launch_bounds__(256) void ln_kernel(const float* __restrict__ Y,
                                                 const float* __restrict__ g,
                                                 const float* __restrict__ be,
                                                 f16* __restrict__ hpad) {
    int row = blockIdx.x * 4 + (threadIdx.x >> 6);
    int lane = threadIdx.x & 63;
    const float4* y = (const float4*)(Y + (size_t)row * C_);
    float4 v0 = y[lane * 2], v1 = y[lane * 2 + 1];
    float s = v0.x + v0.y + v0.z + v0.w + v1.x + v1.y + v1.z + v1.w;
    float q = v0.x * v0.x + v0.y * v0.y + v0.z * v0.z + v0.w * v0.w +
              v1.x * v1.x + v1.y * v1.y + v1.z * v1.z + v1.w * v1.w;
#pragma unroll
    for (int m = 32; m; m >>= 1) { s += __shfl_xor(s, m, 64); q += __shfl_xor(q, m, 64); }
    float mu = s * (1.f / 512.f);
    float x = q * (1.f / 512.f) - mu * mu + 1e-5f;
    float rs = rsqrtf(x);
    rs = rs * (1.5f - 0.5f * x * rs * rs);   // Newton refine
    const float4* g4 = (const float4*)g;
    const float4* b4 = (const float4*)be;
    float4 g0 = g4[lane * 2], g1 = g4[lane * 2 + 1];
    float4 e0 = b4[lane * 2], e1 = b4[lane * 2 + 1];
    f16x8 h;
    h[0] = (f16)((v0.x - mu) * rs * g0.x + e0.x);
    h[1] = (f16)((v0.y - mu) * rs * g0.y + e0.y);
    h[2] = (f16)((v0.z - mu) * rs * g0.z + e0.z);
    h[3] = (f16)((v0.w - mu) * rs * g0.w + e0.w);
    h[4] = (f16)((v1.x - mu) * rs * g1.x + e1.x);
    h[5] = (f16)((v1.y - mu) * rs * g1.y + e1.y);
    h[6] = (f16)((v1.z - mu) * rs * g1.z + e1.z);
    h[7] = (f16)((v1.w - mu) * rs * g1.w + e1.w);
    int b = row >> 10, t = row & 1023;
    *(f16x8*)(hpad + ((size_t)(b * TP_ + t + 1)) * C_ + lane * 8) = h;
}

// ---------------------------------------------------------------------------
// LN2 fused with Linear head: pred[row] = mask * (dot(LN(y), lin_w) + lin_b)
__global__ __launch_bounds__(256) void ln2pred_kernel(const float* __restrict__ Y,
                                                      const float* __restrict__ g,
                                                      const float* __restrict__ be,
                                                      const float* __restrict__ lw,
                                                      const float* __restrict__ lb,
                                                      const int* __restrict__ tlen,
                                                      float* __restrict__ pred) {
    int row = blockIdx.x * 4 + (threadIdx.x >> 6);
    int lane = threadIdx.x & 63;
    const float4* y = (const float4*)(Y + (size_t)row * C_);
    float4 v0 = y[lane * 2], v1 = y[lane * 2 + 1];
    float s = v0.x + v0.y + v0.z + v0.w + v1.x + v1.y + v1.z + v1.w;
    float q = v0.x * v0.x + v0.y * v0.y + v0.z * v0.z + v0.w * v0.w +
              v1.x * v1.x + v1.y * v1.y + v1.z * v1.z + v1.w * v1.w;
#pragma unroll
    for (int m = 32; m; m >>= 1) { s += __shfl_xor(s, m, 64); q += __shfl_xor(q, m, 64); }
    float mu = s * (1.f / 512.f);
    float x = q * (1.f / 512.f) - mu * mu + 1e-5f;
    float rs = rsqrtf(x);
    rs = rs * (1.5f - 0.5f * x * rs * rs);
    const float4* g4 = (const float4*)g;
    const float4* b4 = (const float4*)be;
    const float4* w4 = (const float4*)lw;
    float4 g0 = g4[lane * 2], g1 = g4[lane * 2 + 1];
    float4 e0 = b4[lane * 2], e1 = b4[lane * 2 + 1];
    float4 w0 = w4[lane * 2], w1 = w4[lane * 2 + 1];
    float p = ((v0.x - mu) * rs * g0.x + e0.x) * w0.x +
              ((v0.y - mu) * rs * g0.y + e0.y) * w0.y +
              ((v0.z - mu) * rs * g0.z + e0.z) * w0.z +
              ((v0.w - mu) * rs * g0.w + e0.w) * w0.w +
              ((v1.x - mu) * rs * g1.x + e1.x) * w1.x +
              ((v1.y - mu) * rs * g1.y + e1.y) * w1.y +
              ((v1.z - mu) * rs * g1.z + e1.z) * w1.z +
              ((v1.w - mu) * rs * g1.w + e1.w) * w1.w;
#pragma unroll
    for (int m = 32; m; m >>= 1) p += __shfl_xor(p, m, 64);
    if (lane == 0) {
        int b = row >> 10, t = row & 1023;
        pred[row] = (t < tlen[b]) ? (p + lb[0]) : 0.f;
    }
}

// ---------------------------------------------------------------------------
// regulate gather: wave per output frame row; precomputed idx (no search).
__global__ __launch_bounds__(256) void gather_kernel(const float* __restrict__ batch,
                                                     const int* __restrict__ idxarr,
                                                     const int* __restrict__ total,
                                                     float* __restrict__ out) {
    int gw = blockIdx.x * 4 + (threadIdx.x >> 6);  // 0 .. B_*LMAX_-1
    int lane = threadIdx.x & 63;
    int b = gw >> 12;
    int l = gw & (LMAX_ - 1);
    int tot = total[b];
    float4* dst = (float4*)(out + ((size_t)b * LMAX_ + l) * C_);
    if (l < tot) {
        int idx = idxarr[gw];
        const float4* src = (const float4*)(batch + ((size_t)b * T_ + idx) * C_);
        dst[lane] = src[lane];
        dst[lane + 64] = src[lane + 64];
    } else {
        float4 z = {0.f, 0.f, 0.f, 0.f};
        dst[lane] = z;
        dst[lane + 64] = z;
    }
}

// ---------------------------------------------------------------------------
extern "C" void kernel_launch(void* const* d_in, const int* in_sizes, int n_in,
                              void* d_out, int out_size, void* d_ws, size_t ws_size,
                              hipStream_t stream) {
    const float* batch = (const float*)d_in[0];
    const int* tlen    = (const int*)d_in[1];
    const int* durs    = (const int*)d_in[3];
    const float* w1  = (const float*)d_in[4];
    const float* b1  = (const float*)d_in[5];
    const float* g1  = (const float*)d_in[6];
    const float* be1 = (const float*)d_in[7];
    const float* w2  = (const float*)d_in[8];
    const float* b2  = (const float*)d_in[9];
    const float* g2  = (const float*)d_in[10];
    const float* be2 = (const float*)d_in[11];
    const float* lw  = (const float*)d_in[12];
    const float* lb  = (const float*)d_in[13];

    float* out      = (float*)d_out;
    float* mel_out  = out + (size_t)B_ * LMAX_ * C_;
    float* pred_out = mel_out + B_;

    char* ws    = (char*)d_ws;
    f16* xpad   = (f16*)(ws + XPAD_OFF);
    f16* h1pad  = (f16*)(ws + H1PAD_OFF);
    f16* w1t    = (f16*)(ws + W1T_OFF);
    f16* w2t    = (f16*)(ws + W2T_OFF);
    float* yws  = (float*)(ws + YWS_OFF);
    int* tot    = (int*)(ws + TOT_OFF);
    int* idxarr = (int*)(ws + IDX_OFF);

    prep_pad<<<B_ * TP_ / 4, 256, 0, stream>>>(batch, xpad, h1pad);
    prep_w<<<dim3(512, 2), 256, 0, stream>>>(w1, w2, w1t, w2t);
    scan_kernel<<<B_, 1024, 0, stream>>>(durs, tlen, idxarr, tot, mel_out);
    // --- gemm1 launched 3x (2 redundant, idempotent) for timing attribution ---
    gemm_convln<<<dim3(256, 4), 256, 0, stream>>>(xpad, w1t, b1, yws);
    gemm_convln<<<dim3(256, 4), 256, 0, stream>>>(xpad, w1t, b1, yws);
    gemm_convln<<<dim3(256, 4), 256, 0, stream>>>(xpad, w1t, b1, yws);
    ln_kernel<<<8192, 256, 0, stream>>>(yws, g1, be1, h1pad);
    gemm_convln<<<dim3(256, 4), 256, 0, stream>>>(h1pad, w2t, b2, yws);
    ln2pred_kernel<<<8192, 256, 0, stream>>>(yws, g2, be2, lw, lb, tlen, pred_out);
    gather_kernel<<<B_ * LMAX_ / 4, 256, 0, stream>>>(batch, idxarr, tot, out);
}

// Round 7
// 466.733 us; speedup vs baseline: 1.3058x; 1.3058x over previous
//
#include <hip/hip_runtime.h>
#include <hip/hip_bf16.h>
#include <stdint.h>

// R6 measurement: t_gemm ≈ 60us each (R6 - R2 = 120us for 2 dup dispatches).
// ~250us of dur_us is fixed harness poison/restore overhead (1.07GB ws fill
// at 167us visible in profile + d_out poison + d_in restore). Controllable
// budget ~239us: gemm 2x60, gather ~50, prep_pad ~25, ln ~20, ln2pred ~12,
// scan ~10, prep_w ~5, gaps. R7: LDS-read-bound gemm -> 64x128 wave tiles
// (24 ds_read_b128 : 64 MFMA vs 16:32), staging 786->576MB; yws in fp16.

typedef _Float16 f16;
typedef _Float16 f16x8 __attribute__((ext_vector_type(8)));
typedef float f32x4 __attribute__((ext_vector_type(4)));

#define B_    32
#define T_    1024
#define TP_   1026
#define C_    512
#define LMAX_ 4096
#define KDIM  1536

// workspace byte offsets (all 256-aligned)
#define XPAD_OFF   0u
#define H1PAD_OFF  33619968u     // 32*1026*512*2
#define W1T_OFF    67239936u
#define W2T_OFF    68812800u
#define YWS_OFF    70385664u     // now f16, 32 MB
#define TOT_OFF    137494528u
#define IDX_OFF    137495040u

#define AS1C(p) ((const __attribute__((address_space(1))) void*)(p))
#define AS3(p)  ((__attribute__((address_space(3))) void*)(p))

// ---------------------------------------------------------------------------
// prep: xpad = fp16(batch) with zero guard rows at t=-1 and t=T; also zero
// h1pad guard rows (ws is re-poisoned before every launch).
__global__ __launch_bounds__(256) void prep_pad(const float* __restrict__ batch,
                                                f16* __restrict__ xpad,
                                                f16* __restrict__ h1pad) {
    int row = blockIdx.x * 4 + (threadIdx.x >> 6);   // 0 .. B_*TP_-1
    int lane = threadIdx.x & 63;
    int b = row / TP_, tt = row % TP_;
    size_t dsto = (size_t)row * C_ + lane * 8;
    if (tt == 0 || tt == TP_ - 1) {
        f16x8 z = {};
        *(f16x8*)(xpad + dsto) = z;
        *(f16x8*)(h1pad + dsto) = z;
    } else {
        const float* src = batch + ((size_t)(b * T_ + tt - 1)) * C_ + lane * 8;
        float4 v0 = ((const float4*)src)[0];
        float4 v1 = ((const float4*)src)[1];
        f16x8 h;
        h[0] = (f16)v0.x; h[1] = (f16)v0.y; h[2] = (f16)v0.z; h[3] = (f16)v0.w;
        h[4] = (f16)v1.x; h[5] = (f16)v1.y; h[6] = (f16)v1.z; h[7] = (f16)v1.w;
        *(f16x8*)(xpad + dsto) = h;
    }
}

// ---------------------------------------------------------------------------
// prep weights: wt[o][tap*512+i] = w[o][i][tap], fp16.  w is [512][512][3].
__global__ __launch_bounds__(256) void prep_w(const float* __restrict__ w1,
                                              const float* __restrict__ w2,
                                              f16* __restrict__ w1t,
                                              f16* __restrict__ w2t) {
    int o = blockIdx.x;
    const float* w = blockIdx.y ? w2 : w1;
    f16* wt = blockIdx.y ? w2t : w1t;
    for (int j = threadIdx.x; j < KDIM; j += 256) {
        int tap = j >> 9, i = j & 511;
        wt[(size_t)o * KDIM + j] = (f16)w[(size_t)o * KDIM + i * 3 + tap];
    }
}

// ---------------------------------------------------------------------------
// per-batch duration scan + direct inverse-map scatter (searchsorted inverse).
__global__ __launch_bounds__(1024) void scan_kernel(const int* __restrict__ dur,
                                                    const int* __restrict__ tlen,
                                                    int* __restrict__ idxarr,
                                                    int* __restrict__ total,
                                                    float* __restrict__ mel_out) {
    int b = blockIdx.x, t = threadIdx.x;
    __shared__ int sd[1024];
    __shared__ int sv[1024];
    int L = tlen[b];
    int valid = (t < L) ? 1 : 0;
    int d = valid ? dur[b * T_ + t] : 0;
    sd[t] = d; sv[t] = valid;
    __syncthreads();
    for (int off = 1; off < 1024; off <<= 1) {
        int x = 0, y = 0;
        if (t >= off) { x = sd[t - off]; y = sv[t - off]; }
        __syncthreads();
        sd[t] += x; sv[t] += y;
        __syncthreads();
    }
    int totd = sd[1023];
    int cur  = (totd == 0) ? sv[t] : sd[t];
    int prev = (t == 0) ? 0 : ((totd == 0) ? sv[t - 1] : sd[t - 1]);
    for (int f = prev; f < cur; f++) idxarr[b * LMAX_ + f] = t;
    if (t == 1023) {
        int tt = (totd == 0) ? sv[1023] : totd;
        total[b] = tt;
        mel_out[b] = (float)tt;
    }
}

// ---------------------------------------------------------------------------
// implicit-GEMM conv: Y(f16) = relu(A @ Bw^T + bias).
// BM=128 x BN=256 block, 4 waves, wave tile 64x128 (4x8 frags of 16x16x32):
// 24 ds_read_b128 feed 64 MFMA per k-iter (vs 16:32 before) -> LDS-read
// pressure per output drops 1.33x; staging 576MB total (A x2, B x128) vs
// 786MB at BN=128.  LDS 48KB -> 2 blocks/CU (cross-block overlap hides the
// barrier vmcnt drain, the R2 mechanism that measured best).
// XOR granule swizzle: LDS[r][s] holds global granule s^(r&7).
__global__ __launch_bounds__(256, 2) void gemm_k(const f16* __restrict__ A,
                                                 const f16* __restrict__ Bw,
                                                 const float* __restrict__ bias,
                                                 f16* __restrict__ Y) {
    __shared__ f16 As[128 * 64];   // 16 KB
    __shared__ f16 Bs[256 * 64];   // 32 KB
    const int tid = threadIdx.x;
    const int lane = tid & 63;
    const int w = tid >> 6;        // 0..3
    const int m0 = blockIdx.x * 128;
    const int n0 = blockIdx.y * 256;
    const int arow0 = (m0 >> 10) * TP_ + (m0 & 1023);
    const int wm = (w & 1) * 64;
    const int wn = (w >> 1) * 128;

    f32x4 acc[4][8];
#pragma unroll
    for (int i = 0; i < 4; i++)
#pragma unroll
        for (int j = 0; j < 8; j++) acc[i][j] = (f32x4){0.f, 0.f, 0.f, 0.f};

    const int lrow = lane >> 3;                  // 0..7
    const int gran = (lane & 7) ^ lrow;          // swizzled source granule
    const f16* aB = A + (size_t)(arow0 + lrow) * C_ + gran * 8;
    const f16* bB = Bw + (size_t)(n0 + lrow) * KDIM + gran * 8;

    for (int kk = 0; kk < KDIM; kk += 64) {
        __syncthreads();
#pragma unroll
        for (int i = 0; i < 4; i++) {           // A: 16 wave-loads / 4 waves
            const int rb = (w + i * 4) * 8;
            __builtin_amdgcn_global_load_lds(AS1C(aB + (size_t)rb * C_ + kk),
                                             AS3(&As[rb * 64]), 16, 0, 0);
        }
#pragma unroll
        for (int j = 0; j < 8; j++) {           // B: 32 wave-loads / 4 waves
            const int rb = (w + j * 4) * 8;
            __builtin_amdgcn_global_load_lds(AS1C(bB + (size_t)rb * KDIM + kk),
                                             AS3(&Bs[rb * 64]), 16, 0, 0);
        }
        __syncthreads();   // drains vmcnt -> LDS tiles complete
#pragma unroll
        for (int ks = 0; ks < 2; ks++) {
            const int sl = ((ks << 2) + (lane >> 4)) ^ (lane & 7);
            f16x8 af[4], bf[8];
#pragma unroll
            for (int mi = 0; mi < 4; mi++)
                af[mi] = *(const f16x8*)&As[(wm + mi * 16 + (lane & 15)) * 64 + sl * 8];
#pragma unroll
            for (int ni = 0; ni < 8; ni++)
                bf[ni] = *(const f16x8*)&Bs[(wn + ni * 16 + (lane & 15)) * 64 + sl * 8];
#pragma unroll
            for (int mi = 0; mi < 4; mi++)
#pragma unroll
                for (int ni = 0; ni < 8; ni++)
                    acc[mi][ni] = __builtin_amdgcn_mfma_f32_16x16x32_f16(
                        af[mi], bf[ni], acc[mi][ni], 0, 0, 0);
        }
    }

    const int col = lane & 15;
    const int row4 = (lane >> 4) * 4;
#pragma unroll
    for (int ni = 0; ni < 8; ni++) {
        int n = n0 + wn + ni * 16 + col;
        float bn = bias[n];
#pragma unroll
        for (int mi = 0; mi < 4; mi++) {
#pragma unroll
            for (int r = 0; r < 4; r++) {
                int m = m0 + wm + mi * 16 + row4 + r;
                float v = acc[mi][ni][r] + bn;
                Y[(size_t)m * C_ + n] = (f16)(v > 0.f ? v : 0.f);
            }
        }
    }
}

// ---------------------------------------------------------------------------
// LayerNorm over C=512 (input f16), wave per row, write fp16 into h1pad.
__global__ __launch_bounds__(256) void ln_kernel(const f16* __restrict__ Y,
                                                 const float* __restrict__ g,
                                                 const float* __restrict__ be,
                                                 f16* __restrict__ hpad) {
    int row = blockIdx.x * 4 + (threadIdx.x >> 6);
    int lane = threadIdx.x & 63;
    f16x8 yv = *(const f16x8*)(Y + (size_t)row * C_ + lane * 8);
    float v[8];
#pragma unroll
    for (int i = 0; i < 8; i++) v[i] = (float)yv[i];
    float s = 0.f, q = 0.f;
#pragma unroll
    for (int i = 0; i < 8; i++) { s += v[i]; q += v[i] * v[i]; }
#pragma unroll
    for (int m = 32; m; m >>= 1) { s += __shfl_xor(s, m, 64); q += __shfl_xor(q, m, 64); }
    float mu = s * (1.f / 512.f);
    float x = q * (1.f / 512.f) - mu * mu + 1e-5f;
    float rs = rsqrtf(x);
    rs = rs * (1.5f - 0.5f * x * rs * rs);   // Newton refine
    const float4 g0 = ((const float4*)g)[lane * 2], g1 = ((const float4*)g)[lane * 2 + 1];
    const float4 e0 = ((const float4*)be)[lane * 2], e1 = ((const float4*)be)[lane * 2 + 1];
    f16x8 h;
    h[0] = (f16)((v[0] - mu) * rs * g0.x + e0.x);
    h[1] = (f16)((v[1] - mu) * rs * g0.y + e0.y);
    h[2] = (f16)((v[2] - mu) * rs * g0.z + e0.z);
    h[3] = (f16)((v[3] - mu) * rs * g0.w + e0.w);
    h[4] = (f16)((v[4] - mu) * rs * g1.x + e1.x);
    h[5] = (f16)((v[5] - mu) * rs * g1.y + e1.y);
    h[6] = (f16)((v[6] - mu) * rs * g1.z + e1.z);
    h[7] = (f16)((v[7] - mu) * rs * g1.w + e1.w);
    int b = row >> 10, t = row & 1023;
    *(f16x8*)(hpad + ((size_t)(b * TP_ + t + 1)) * C_ + lane * 8) = h;
}

// ---------------------------------------------------------------------------
// LN2 (input f16) fused with Linear head: pred = mask * (dot(LN(y), lw) + lb)
__global__ __launch_bounds__(256) void ln2pred_kernel(const f16* __restrict__ Y,
                                                      const float* __restrict__ g,
                                                      const float* __restrict__ be,
                                                      const float* __restrict__ lw,
                                                      const float* __restrict__ lb,
                                                      const int* __restrict__ tlen,
                                                      float* __restrict__ pred) {
    int row = blockIdx.x * 4 + (threadIdx.x >> 6);
    int lane = threadIdx.x & 63;
    f16x8 yv = *(const f16x8*)(Y + (size_t)row * C_ + lane * 8);
    float v[8];
#pragma unroll
    for (int i = 0; i < 8; i++) v[i] = (float)yv[i];
    float s = 0.f, q = 0.f;
#pragma unroll
    for (int i = 0; i < 8; i++) { s += v[i]; q += v[i] * v[i]; }
#pragma unroll
    for (int m = 32; m; m >>= 1) { s += __shfl_xor(s, m, 64); q += __shfl_xor(q, m, 64); }
    float mu = s * (1.f / 512.f);
    float x = q * (1.f / 512.f) - mu * mu + 1e-5f;
    float rs = rsqrtf(x);
    rs = rs * (1.5f - 0.5f * x * rs * rs);
    const float4 g0 = ((const float4*)g)[lane * 2], g1 = ((const float4*)g)[lane * 2 + 1];
    const float4 e0 = ((const float4*)be)[lane * 2], e1 = ((const float4*)be)[lane * 2 + 1];
    const float4 w0 = ((const float4*)lw)[lane * 2], w1 = ((const float4*)lw)[lane * 2 + 1];
    float p = ((v[0] - mu) * rs * g0.x + e0.x) * w0.x +
              ((v[1] - mu) * rs * g0.y + e0.y) * w0.y +
              ((v[2] - mu) * rs * g0.z + e0.z) * w0.z +
              ((v[3] - mu) * rs * g0.w + e0.w) * w0.w +
              ((v[4] - mu) * rs * g1.x + e1.x) * w1.x +
              ((v[5] - mu) * rs * g1.y + e1.y) * w1.y +
              ((v[6] - mu) * rs * g1.z + e1.z) * w1.z +
              ((v[7] - mu) * rs * g1.w + e1.w) * w1.w;
#pragma unroll
    for (int m = 32; m; m >>= 1) p += __shfl_xor(p, m, 64);
    if (lane == 0) {
        int b = row >> 10, t = row & 1023;
        pred[row] = (t < tlen[b]) ? (p + lb[0]) : 0.f;
    }
}

// ---------------------------------------------------------------------------
// regulate gather: wave per output frame row; precomputed idx (no search).
__global__ __launch_bounds__(256) void gather_kernel(const float* __restrict__ batch,
                                                     const int* __restrict__ idxarr,
                                                     const int* __restrict__ total,
                                                     float* __restrict__ out) {
    int gw = blockIdx.x * 4 + (threadIdx.x >> 6);  // 0 .. B_*LMAX_-1
    int lane = threadIdx.x & 63;
    int b = gw >> 12;
    int l = gw & (LMAX_ - 1);
    int tot = total[b];
    float4* dst = (float4*)(out + ((size_t)b * LMAX_ + l) * C_);
    if (l < tot) {
        int idx = idxarr[gw];
        const float4* src = (const float4*)(batch + ((size_t)b * T_ + idx) * C_);
        dst[lane] = src[lane];
        dst[lane + 64] = src[lane + 64];
    } else {
        float4 z = {0.f, 0.f, 0.f, 0.f};
        dst[lane] = z;
        dst[lane + 64] = z;
    }
}

// ---------------------------------------------------------------------------
extern "C" void kernel_launch(void* const* d_in, const int* in_sizes, int n_in,
                              void* d_out, int out_size, void* d_ws, size_t ws_size,
                              hipStream_t stream) {
    const float* batch = (const float*)d_in[0];
    const int* tlen    = (const int*)d_in[1];
    const int* durs    = (const int*)d_in[3];
    const float* w1  = (const float*)d_in[4];
    const float* b1  = (const float*)d_in[5];
    const float* g1  = (const float*)d_in[6];
    const float* be1 = (const float*)d_in[7];
    const float* w2  = (const float*)d_in[8];
    const float* b2  = (const float*)d_in[9];
    const float* g2  = (const float*)d_in[10];
    const float* be2 = (const float*)d_in[11];
    const float* lw  = (const float*)d_in[12];
    const float* lb  = (const float*)d_in[13];

    float* out      = (float*)d_out;
    float* mel_out  = out + (size_t)B_ * LMAX_ * C_;
    float* pred_out = mel_out + B_;

    char* ws    = (char*)d_ws;
    f16* xpad   = (f16*)(ws + XPAD_OFF);
    f16* h1pad  = (f16*)(ws + H1PAD_OFF);
    f16* w1t    = (f16*)(ws + W1T_OFF);
    f16* w2t    = (f16*)(ws + W2T_OFF);
    f16* yws    = (f16*)(ws + YWS_OFF);
    int* tot    = (int*)(ws + TOT_OFF);
    int* idxarr = (int*)(ws + IDX_OFF);

    prep_pad<<<B_ * TP_ / 4, 256, 0, stream>>>(batch, xpad, h1pad);
    prep_w<<<dim3(512, 2), 256, 0, stream>>>(w1, w2, w1t, w2t);
    scan_kernel<<<B_, 1024, 0, stream>>>(durs, tlen, idxarr, tot, mel_out);
    gemm_k<<<dim3(256, 2), 256, 0, stream>>>(xpad, w1t, b1, yws);
    ln_kernel<<<8192, 256, 0, stream>>>(yws, g1, be1, h1pad);
    gemm_k<<<dim3(256, 2), 256, 0, stream>>>(h1pad, w2t, b2, yws);
    ln2pred_kernel<<<8192, 256, 0, stream>>>(yws, g2, be2, lw, lb, tlen, pred_out);
    gather_kernel<<<B_ * LMAX_ / 4, 256, 0, stream>>>(batch, idxarr, tot, out);
}